// Round 7
// baseline (286.724 us; speedup 1.0000x reference)
//
#include <hip/hip_runtime.h>
#include <hip/hip_bf16.h>

// MoE expert pool: E=8, D=512, H=2048, M=8192 tokens, top-2 routing.
// Both GEMMs: 4-phase pipelined template, halves staged 3-4 phases before use,
// counted vmcnt from an explicit ledger, XOR-swizzled chunk staging, setprio.
// R7: fix gemm2 A-staging (H1 is slot-indexed; R6 wrongly went through stok[]).

#define NEXP 8
#define DIM 512
#define HID 2048
#define MTOK 8192
#define PMAX (2*MTOK)
#define TM 256
#define MT 72
#define NT1 (DIM/64)    // 8 K-tiles (gemm1)
#define NT2 (HID/64)    // 32 K-tiles (gemm2)

typedef __bf16 bf16;
typedef __bf16 bf16x8 __attribute__((ext_vector_type(8)));
typedef float  f32x4  __attribute__((ext_vector_type(4)));

#define WAITVM(N) asm volatile("s_waitcnt vmcnt(" #N ")" ::: "memory")
#define LGKM0     asm volatile("s_waitcnt lgkmcnt(0)" ::: "memory")
#define SCHED0    __builtin_amdgcn_sched_barrier(0)
#define BAR       __builtin_amdgcn_s_barrier
#define PRIO(x)   __builtin_amdgcn_s_setprio(x)

__device__ __forceinline__ void gload16(const bf16* g, bf16* l) {
  __builtin_amdgcn_global_load_lds(
      (const __attribute__((address_space(1))) void*)g,
      (__attribute__((address_space(3))) void*)l, 16, 0, 0);
}

// ---- fp32 -> bf16 convert (tokens) ----
__global__ __launch_bounds__(256) void k_cvt_x(const float* __restrict__ in,
                                               bf16* __restrict__ out, int n4) {
  int i = blockIdx.x*256 + threadIdx.x;
  if (i >= n4) return;
  float4 v = ((const float4* __restrict__)in)[i];
  bf16 o[4];
  o[0]=(bf16)v.x; o[1]=(bf16)v.y; o[2]=(bf16)v.z; o[3]=(bf16)v.w;
  *(uint2*)&out[(size_t)i*4] = *(uint2*)o;
}

// ---- fp32 [E][R][C] -> bf16 [E][C][R] transpose+convert ----
__global__ __launch_bounds__(256) void k_tcvt2(const float* __restrict__ in0,
                                               const float* __restrict__ in1,
                                               bf16* __restrict__ out0,
                                               bf16* __restrict__ out1, int R, int C) {
  __shared__ __align__(16) bf16 t[64][72];
  const int z = blockIdx.z;
  const int e = z & (NEXP-1);
  const float* __restrict__ pin = ((z < NEXP) ? in0 : in1) + (size_t)e*R*C;
  bf16* __restrict__ pout = ((z < NEXP) ? out0 : out1) + (size_t)e*R*C;
  const int c0 = blockIdx.x*64, r0 = blockIdx.y*64;
  const int tid = threadIdx.x;
  const int rr = tid>>4, cc4 = (tid&15)*4;
#pragma unroll
  for (int i=0;i<4;i++){
    int r = i*16 + rr;
    float4 v = *(const float4*)&pin[(size_t)(r0+r)*C + c0 + cc4];
    t[cc4+0][r]=(bf16)v.x; t[cc4+1][r]=(bf16)v.y;
    t[cc4+2][r]=(bf16)v.z; t[cc4+3][r]=(bf16)v.w;
  }
  __syncthreads();
#pragma unroll
  for (int i=0;i<4;i++){
    int c = i*16 + rr;
    *(uint2*)&pout[(size_t)(c0+c)*R + r0 + cc4] = *(uint2*)&t[c][cc4];
  }
}

// ---- routing: count tokens per expert ----
__global__ __launch_bounds__(256) void k_count(const float* __restrict__ disp,
                                               int* __restrict__ cnt) {
  __shared__ int lc[NEXP];
  int t = threadIdx.x;
  if (t < NEXP) lc[t] = 0;
  __syncthreads();
  int m = blockIdx.x*256 + t;
  float4 d0 = *(const float4*)&disp[(size_t)m*NEXP];
  float4 d1 = *(const float4*)&disp[(size_t)m*NEXP+4];
  if (d0.x>0.f) atomicAdd(&lc[0],1);
  if (d0.y>0.f) atomicAdd(&lc[1],1);
  if (d0.z>0.f) atomicAdd(&lc[2],1);
  if (d0.w>0.f) atomicAdd(&lc[3],1);
  if (d1.x>0.f) atomicAdd(&lc[4],1);
  if (d1.y>0.f) atomicAdd(&lc[5],1);
  if (d1.z>0.f) atomicAdd(&lc[6],1);
  if (d1.w>0.f) atomicAdd(&lc[7],1);
  __syncthreads();
  if (t < NEXP) atomicAdd(&cnt[t], lc[t]);
}

// ---- prefix + tile list (TM=256, shared by both gemms) ----
__global__ void k_scan(const int* __restrict__ cnt, int* __restrict__ base,
                       int* __restrict__ te, int* __restrict__ trow, int* __restrict__ tn) {
  __shared__ int sb[NEXP+1], st[NEXP+1], sc[NEXP];
  if (threadIdx.x == 0){
    int b=0, t=0;
    for (int e=0;e<NEXP;e++){
      sb[e]=b; st[e]=t; sc[e]=cnt[e]; base[e]=b;
      b += sc[e];
      t += (sc[e]+TM-1)/TM;
    }
    sb[NEXP]=b; st[NEXP]=t;
  }
  __syncthreads();
  for (int idx=threadIdx.x; idx<MT; idx+=blockDim.x){
    int e=-1;
#pragma unroll
    for (int q=0;q<NEXP;q++) if (idx>=st[q] && idx<st[q+1]) e=q;
    if (e>=0){
      int k = idx - st[e];
      int nr = sc[e] - k*TM; if (nr>TM) nr=TM;
      te[idx]=e; trow[idx]=sb[e]+k*TM; tn[idx]=nr;
    } else te[idx]=-1;
  }
}

// ---- fill slot lists + per-token slot map ----
__global__ __launch_bounds__(256) void k_fill(const float* __restrict__ disp,
    const float* __restrict__ comb, const float* __restrict__ scales,
    const int* __restrict__ base, int* __restrict__ fillc,
    int* __restrict__ stok, float* __restrict__ sw, int* __restrict__ sslot) {
  int m = blockIdx.x*256 + threadIdx.x;
  int jj = 0;
#pragma unroll
  for (int e=0;e<NEXP;e++){
    float dv = disp[(size_t)m*NEXP + e];
    if (dv > 0.f) {
      int s = atomicAdd(&fillc[e], 1);
      int g = base[e] + s;
      stok[g] = m;
      sw[g] = comb[(size_t)m*NEXP + e] * scales[e];
      if (jj < 2) sslot[m*2 + jj] = g;
      jj++;
    }
  }
}

// ---- GEMM1: H1 = gelu(X@Wg)*(X@Wv); BM256 x BN128(g&v), 8 waves 2Mx4N ----
// Halves (16KB, 2 loads each): A0 = per-wave rows 0-63, A1 = 64-127;
// B half ht(=ni): 128 rows = [wc(4)][gv(2)][16], col = n0+wc*32+ht*16+c.
// Phase cycle (A0B0)(A0B1)(A1B1)(A1B0); stage t+1: ph1 A0, ph2 B0, ph3 B1, ph4 A1.
// Ledger: entry-outstanding 8 -> vmcnt(4) at ends of ph1,ph2,ph4; none ph3.
__global__ __launch_bounds__(512, 2) void k_gemm1(const bf16* __restrict__ Xb,
    const bf16* __restrict__ WgT, const bf16* __restrict__ WvT,
    const int* __restrict__ te, const int* __restrict__ trow, const int* __restrict__ tn,
    const int* __restrict__ stok, bf16* __restrict__ H1) {
  const int tile = blockIdx.y;
  const int e = te[tile];
  if (e < 0) return;
  const int row0 = trow[tile], nrows = tn[tile];
  const int n0 = blockIdx.x*128;
  __shared__ __align__(16) bf16 Ab[2][2][8192];   // 64 KB
  __shared__ __align__(16) bf16 Bb[2][2][8192];   // 64 KB
  const int tid = threadIdx.x, lane = tid&63, wid = tid>>6;
  const int wr = wid>>2, wc = wid&3;
  const bf16* __restrict__ wgp = WgT + (size_t)e*HID*DIM;
  const bf16* __restrict__ wvp = WvT + (size_t)e*HID*DIM;

  const bf16 *ap[2][2], *bp[2][2];
#pragma unroll
  for (int ht=0; ht<2; ht++)
#pragma unroll
    for (int i=0;i<2;i++){
      int c = i*512 + tid, lr = c>>3, q = c&7, qs = q ^ (lr&7);
      int arow = (lr>>6)*128 + ht*64 + (lr&63);
      int gr = row0 + ((arow < nrows) ? arow : 0);
      ap[ht][i] = Xb + (size_t)stok[gr]*DIM + qs*8;
      int col = n0 + (lr>>5)*32 + ht*16 + (lr&15);
      bp[ht][i] = (((lr>>4)&1) ? wvp : wgp) + (size_t)col*DIM + qs*8;
    }
  const int d0 = (tid&448)*8, d1 = 4096 + d0;

#define SA1(BI,HT,KT) { gload16(ap[HT][0]+(KT)*64, &Ab[BI][HT][0]+d0); \
                        gload16(ap[HT][1]+(KT)*64, &Ab[BI][HT][0]+d1); }
#define SB1(BI,HT,KT) { gload16(bp[HT][0]+(KT)*64, &Bb[BI][HT][0]+d0); \
                        gload16(bp[HT][1]+(KT)*64, &Bb[BI][HT][0]+d1); }

  const int rlo = lane&15, kq = lane>>4;
  const int ko0 = (kq ^ (rlo&7))*8, ko1 = ((4+kq) ^ (rlo&7))*8;

  bf16x8 a[4][2], g[2], v[2];
  f32x4 ag[8][2] = {}, av[8][2] = {};

#define RA1(HT,BI) { _Pragma("unroll") for (int m_=0;m_<4;m_++){           \
    const bf16* p_ = &Ab[BI][HT][(wr*64 + m_*16 + rlo)*64];                \
    a[m_][0] = *(const bf16x8*)(p_ + ko0);                                 \
    a[m_][1] = *(const bf16x8*)(p_ + ko1); } }
#define RB1(HT,BI) { const bf16* pg_ = &Bb[BI][HT][(wc*32 + rlo)*64];      \
    const bf16* pv_ = &Bb[BI][HT][(wc*32 + 16 + rlo)*64];                  \
    g[0] = *(const bf16x8*)(pg_ + ko0); g[1] = *(const bf16x8*)(pg_ + ko1);\
    v[0] = *(const bf16x8*)(pv_ + ko0); v[1] = *(const bf16x8*)(pv_ + ko1); }
#define MM1(MH,NI) { _Pragma("unroll") for (int m_=0;m_<4;m_++){                                   \
    ag[(MH)*4+m_][NI] = __builtin_amdgcn_mfma_f32_16x16x32_bf16(a[m_][0], g[0], ag[(MH)*4+m_][NI],0,0,0); \
    ag[(MH)*4+m_][NI] = __builtin_amdgcn_mfma_f32_16x16x32_bf16(a[m_][1], g[1], ag[(MH)*4+m_][NI],0,0,0); \
    av[(MH)*4+m_][NI] = __builtin_amdgcn_mfma_f32_16x16x32_bf16(a[m_][0], v[0], av[(MH)*4+m_][NI],0,0,0); \
    av[(MH)*4+m_][NI] = __builtin_amdgcn_mfma_f32_16x16x32_bf16(a[m_][1], v[1], av[(MH)*4+m_][NI],0,0,0); } }

  // prologue: tile0 halves in FIFO order A0,B0,B1,A1
  SA1(0,0,0); SB1(0,0,0); SB1(0,1,0); SA1(0,1,0);
  WAITVM(4); BAR(); SCHED0;

  for (int t=0; t<NT1-1; ++t){
    const int bi = t&1, nb = bi^1, kn = t+1;
    // ph1 (A0,B0)
    RA1(0,bi); RB1(0,bi);
    SA1(nb,0,kn);
    BAR(); LGKM0; SCHED0;
    PRIO(1); MM1(0,0); PRIO(0);
    WAITVM(4); BAR(); SCHED0;
    // ph2 (A0,B1)
    RB1(1,bi);
    SB1(nb,0,kn);
    BAR(); LGKM0; SCHED0;
    PRIO(1); MM1(0,1); PRIO(0);
    WAITVM(4); BAR(); SCHED0;
    // ph3 (A1,B1)
    RA1(1,bi);
    SB1(nb,1,kn);
    BAR(); LGKM0; SCHED0;
    PRIO(1); MM1(1,1); PRIO(0);
    BAR(); SCHED0;
    // ph4 (A1,B0)
    RB1(0,bi);
    SA1(nb,1,kn);
    BAR(); LGKM0; SCHED0;
    PRIO(1); MM1(1,0); PRIO(0);
    WAITVM(4); BAR(); SCHED0;
  }
  { // tail tile (no staging; drain ledger 4 -> 0)
    const int bi = (NT1-1)&1;
    RA1(0,bi); RB1(0,bi);
    BAR(); LGKM0; SCHED0;
    PRIO(1); MM1(0,0); PRIO(0);
    WAITVM(2); BAR(); SCHED0;
    RB1(1,bi);
    BAR(); LGKM0; SCHED0;
    PRIO(1); MM1(0,1); PRIO(0);
    WAITVM(0); BAR(); SCHED0;
    RA1(1,bi);
    BAR(); LGKM0; SCHED0;
    PRIO(1); MM1(1,1); PRIO(0);
    BAR(); SCHED0;
    RB1(0,bi);
    LGKM0; SCHED0;
    PRIO(1); MM1(1,0); PRIO(0);
  }
#undef SA1
#undef SB1
#undef RA1
#undef RB1
#undef MM1

  const int cb = n0 + wc*32 + rlo;
  const int rb = wr*128 + (lane>>4)*4;
#pragma unroll
  for (int mi=0;mi<8;mi++)
#pragma unroll
    for (int j=0;j<4;j++){
      int r = rb + mi*16 + j;
      if (r < nrows){
#pragma unroll
        for (int ni=0;ni<2;ni++){
          float gg = ag[mi][ni][j], vv = av[mi][ni][j];
          float ge = 0.5f*gg*(1.f + erff(gg*0.70710678118654752f));
          H1[(size_t)(row0+r)*HID + cb + ni*16] = (bf16)(ge*vv);
        }
      }
    }
}

// ---- GEMM2: gout[slot] = (H1@Wo)*sw; BM256 x BN128, 8 waves 4Mx2N ----
// Halves: A (16KB, 2 loads): per-wave rows 0-31 / 32-63 (H1 is SLOT-indexed);
// B (8KB, 1 load): half ht = each wave's ni{0,1}+ht*2, col = n0+wc*64+ht*32+c.
// Ledger (A=2,B=1/half, tile=6): vmcnt ends: ph1=4, ph2=3, ph3=-, ph4=3.
__global__ __launch_bounds__(512, 2) void k_gemm2(const bf16* __restrict__ H1,
    const bf16* __restrict__ WoT,
    const int* __restrict__ te, const int* __restrict__ trow, const int* __restrict__ tn,
    const float* __restrict__ sw, float* __restrict__ gout) {
  const int tile = blockIdx.y;
  const int e = te[tile];
  if (e < 0) return;
  const int row0 = trow[tile], nrows = tn[tile];
  const int n0 = blockIdx.x*128;
  __shared__ __align__(16) bf16 Ab[2][2][8192];   // 64 KB
  __shared__ __align__(16) bf16 Bb[2][2][4096];   // 32 KB
  const int tid = threadIdx.x, lane = tid&63, wid = tid>>6;
  const int wr = wid>>1, wc = wid&1;
  const bf16* __restrict__ wo = WoT + (size_t)e*DIM*HID;

  const bf16 *ap[2][2], *bp[2];
#pragma unroll
  for (int ht=0; ht<2; ht++){
#pragma unroll
    for (int i=0;i<2;i++){
      int c = i*512 + tid, lr = c>>3, q = c&7, qs = q ^ (lr&7);
      int arow = (lr>>5)*64 + ht*32 + (lr&31);
      int gr = row0 + ((arow < nrows) ? arow : 0);   // slot index (H1 is per-slot!)
      ap[ht][i] = H1 + (size_t)gr*HID + qs*8;
    }
    { int c = tid, lr = c>>3, q = c&7, qs = q ^ (lr&7);
      int col = n0 + (lr>>5)*64 + ht*32 + (lr&31);
      bp[ht] = wo + (size_t)col*HID + qs*8;
    }
  }
  const int d0 = (tid&448)*8, d1 = 4096 + d0;

#define SA2(BI,HT,KT) { gload16(ap[HT][0]+(KT)*64, &Ab[BI][HT][0]+d0); \
                        gload16(ap[HT][1]+(KT)*64, &Ab[BI][HT][0]+d1); }
#define SB2(BI,HT,KT) { gload16(bp[HT]+(KT)*64, &Bb[BI][HT][0]+d0); }

  const int rlo = lane&15, kq = lane>>4;
  const int ko0 = (kq ^ (rlo&7))*8, ko1 = ((4+kq) ^ (rlo&7))*8;

  bf16x8 a[2][2], b[2][2];
  f32x4 acc[4][4] = {};

#define RA2(HT,BI) { _Pragma("unroll") for (int m_=0;m_<2;m_++){           \
    const bf16* p_ = &Ab[BI][HT][(wr*32 + m_*16 + rlo)*64];                \
    a[m_][0] = *(const bf16x8*)(p_ + ko0);                                 \
    a[m_][1] = *(const bf16x8*)(p_ + ko1); } }
#define RB2(HT,BI) { _Pragma("unroll") for (int n_=0;n_<2;n_++){           \
    const bf16* p_ = &Bb[BI][HT][(wc*32 + n_*16 + rlo)*64];                \
    b[n_][0] = *(const bf16x8*)(p_ + ko0);                                 \
    b[n_][1] = *(const bf16x8*)(p_ + ko1); } }
#define MM2(MH,NH) { _Pragma("unroll") for (int m_=0;m_<2;m_++)            \
    _Pragma("unroll") for (int n_=0;n_<2;n_++){                            \
    acc[(MH)*2+m_][(NH)*2+n_] = __builtin_amdgcn_mfma_f32_16x16x32_bf16(a[m_][0], b[n_][0], acc[(MH)*2+m_][(NH)*2+n_],0,0,0); \
    acc[(MH)*2+m_][(NH)*2+n_] = __builtin_amdgcn_mfma_f32_16x16x32_bf16(a[m_][1], b[n_][1], acc[(MH)*2+m_][(NH)*2+n_],0,0,0); } }

  SA2(0,0,0); SB2(0,0,0); SB2(0,1,0); SA2(0,1,0);
  WAITVM(3); BAR(); SCHED0;

  for (int t=0; t<NT2-1; ++t){
    const int bi = t&1, nb = bi^1, kn = t+1;
    // ph1 (A0,B0)
    RA2(0,bi); RB2(0,bi);
    SA2(nb,0,kn);
    BAR(); LGKM0; SCHED0;
    PRIO(1); MM2(0,0); PRIO(0);
    WAITVM(4); BAR(); SCHED0;
    // ph2 (A0,B1)
    RB2(1,bi);
    SB2(nb,0,kn);
    BAR(); LGKM0; SCHED0;
    PRIO(1); MM2(0,1); PRIO(0);
    WAITVM(3); BAR(); SCHED0;
    // ph3 (A1,B1)
    RA2(1,bi);
    SB2(nb,1,kn);
    BAR(); LGKM0; SCHED0;
    PRIO(1); MM2(1,1); PRIO(0);
    BAR(); SCHED0;
    // ph4 (A1,B0)
    RB2(0,bi);
    SA2(nb,1,kn);
    BAR(); LGKM0; SCHED0;
    PRIO(1); MM2(1,0); PRIO(0);
    WAITVM(3); BAR(); SCHED0;
  }
  { // tail
    const int bi = (NT2-1)&1;
    RA2(0,bi); RB2(0,bi);
    BAR(); LGKM0; SCHED0;
    PRIO(1); MM2(0,0); PRIO(0);
    WAITVM(2); BAR(); SCHED0;
    RB2(1,bi);
    BAR(); LGKM0; SCHED0;
    PRIO(1); MM2(0,1); PRIO(0);
    WAITVM(0); BAR(); SCHED0;
    RA2(1,bi);
    BAR(); LGKM0; SCHED0;
    PRIO(1); MM2(1,1); PRIO(0);
    BAR(); SCHED0;
    RB2(0,bi);
    LGKM0; SCHED0;
    PRIO(1); MM2(1,0); PRIO(0);
  }
#undef SA2
#undef SB2
#undef RA2
#undef RB2
#undef MM2

  const int cb = n0 + wc*64 + rlo;
  const int rb = wr*64 + (lane>>4)*4;
#pragma unroll
  for (int mi=0;mi<4;mi++)
#pragma unroll
    for (int j=0;j<4;j++){
      int r = rb + mi*16 + j;
      if (r < nrows){
        int slot = row0 + r;
        float wgt = sw[slot];
        float* op = gout + (size_t)slot*DIM + cb;
#pragma unroll
        for (int ni=0;ni<4;ni++)
          op[ni*16] = acc[mi][ni][j] * wgt;
      }
    }
}

// ---- combine: out[tok] = gout[slot0] + gout[slot1] ----
__global__ __launch_bounds__(256) void k_comb(const float* __restrict__ gout,
    const int* __restrict__ sslot, float* __restrict__ out) {
  int idx = blockIdx.x*256 + threadIdx.x;
  int m = idx >> 7, c4 = (idx & 127)*4;
  int s0 = sslot[m*2], s1 = sslot[m*2+1];
  float4 x = *(const float4*)&gout[(size_t)s0*DIM + c4];
  float4 y = *(const float4*)&gout[(size_t)s1*DIM + c4];
  x.x += y.x; x.y += y.y; x.z += y.z; x.w += y.w;
  *(float4*)&out[(size_t)m*DIM + c4] = x;
}

extern "C" void kernel_launch(void* const* d_in, const int* in_sizes, int n_in,
                              void* d_out, int out_size, void* d_ws, size_t ws_size,
                              hipStream_t stream) {
  const float* tokens = (const float*)d_in[0];
  const float* disp   = (const float*)d_in[1];
  const float* comb   = (const float*)d_in[2];
  const float* Wg     = (const float*)d_in[3];
  const float* Wv     = (const float*)d_in[4];
  const float* Wo     = (const float*)d_in[5];
  const float* scales = (const float*)d_in[6];
  float* out = (float*)d_out;

  size_t off = 0;
  char* wsb = (char*)d_ws;
  auto take = [&](size_t bytes)->char* {
    char* q = wsb + off; off += (bytes + 255) & ~(size_t)255; return q;
  };
  int*   cnt   = (int*)  take(NEXP*4);
  int*   basee = (int*)  take(NEXP*4);
  int*   fillc = (int*)  take(NEXP*4);
  int*   te    = (int*)  take(MT*4);
  int*   trow  = (int*)  take(MT*4);
  int*   tnr   = (int*)  take(MT*4);
  int*   stok  = (int*)  take((size_t)PMAX*4);
  float* sw    = (float*)take((size_t)PMAX*4);
  int*   sslot = (int*)  take((size_t)MTOK*2*4);
  bf16*  Xb    = (bf16*) take((size_t)MTOK*DIM*2);
  bf16*  WgT   = (bf16*) take((size_t)NEXP*DIM*HID*2);
  bf16*  WvT   = (bf16*) take((size_t)NEXP*DIM*HID*2);
  bf16*  WoT   = (bf16*) take((size_t)NEXP*DIM*HID*2);
  bf16*  H1    = (bf16*) take((size_t)PMAX*HID*2);
  // gout aliases WgT+WvT: 2 x 16 MiB = 32 MiB; gout = PMAX*DIM*4 = 32 MiB exact.
  float* gout  = (float*)WgT;
  (void)ws_size; (void)in_sizes; (void)n_in; (void)out_size;

  hipMemsetAsync(d_ws, 0, 768, stream);

  k_cvt_x<<<dim3((MTOK*DIM/4)/256), 256, 0, stream>>>(tokens, Xb, MTOK*DIM/4);
  k_tcvt2<<<dim3(HID/64, DIM/64, 2*NEXP), 256, 0, stream>>>(Wg, Wv, WgT, WvT, DIM, HID);
  k_tcvt2<<<dim3(DIM/64, HID/64, NEXP), 256, 0, stream>>>(Wo, Wo, WoT, WoT, HID, DIM);
  k_count<<<dim3(MTOK/256), 256, 0, stream>>>(disp, cnt);
  k_scan <<<1, 64, 0, stream>>>(cnt, basee, te, trow, tnr);
  k_fill <<<dim3(MTOK/256), 256, 0, stream>>>(disp, comb, scales, basee, fillc, stok, sw, sslot);
  k_gemm1<<<dim3(HID/128, MT), 512, 0, stream>>>(Xb, WgT, WvT, te, trow, tnr, stok, H1);
  k_gemm2<<<dim3(DIM/128, MT), 512, 0, stream>>>(H1, WoT, te, trow, tnr, sw, gout);
  k_comb <<<dim3(MTOK*DIM/4/256), 256, 0, stream>>>(gout, sslot, out);
}

// Round 8
// 249.251 us; speedup vs baseline: 1.1503x; 1.1503x over previous
//
#include <hip/hip_runtime.h>
#include <hip/hip_bf16.h>

// MoE expert pool: E=8, D=512, H=2048, M=8192 tokens, top-2 routing.
// R8 = best-of-rounds composition:
//   gemm1: R3-proven 2-phase dbuf 128Mx64N dual-B, 64KB LDS, 256thr (2 blocks/CU).
//   gemm2: R3 structure 128x128 -> gout plain stores (no atomics), 64KB, 2 blocks/CU.
//   k_comb: out[tok] = gout[slot0]+gout[slot1]. Merged weight transposes.

#define NEXP 8
#define DIM 512
#define HID 2048
#define MTOK 8192
#define PMAX (2*MTOK)
#define TM 128
#define MT 144

typedef __bf16 bf16;
typedef __bf16 bf16x8 __attribute__((ext_vector_type(8)));
typedef float  f32x4  __attribute__((ext_vector_type(4)));

#define WAITVM(N) asm volatile("s_waitcnt vmcnt(" #N ")" ::: "memory")
#define SCHED0    __builtin_amdgcn_sched_barrier(0)
#define BAR       __builtin_amdgcn_s_barrier

__device__ __forceinline__ void gload16(const bf16* g, bf16* l) {
  __builtin_amdgcn_global_load_lds(
      (const __attribute__((address_space(1))) void*)g,
      (__attribute__((address_space(3))) void*)l, 16, 0, 0);
}

// ---- fp32 -> bf16 convert (tokens) ----
__global__ __launch_bounds__(256) void k_cvt_x(const float* __restrict__ in,
                                               bf16* __restrict__ out, int n4) {
  int i = blockIdx.x*256 + threadIdx.x;
  if (i >= n4) return;
  float4 v = ((const float4* __restrict__)in)[i];
  bf16 o[4];
  o[0]=(bf16)v.x; o[1]=(bf16)v.y; o[2]=(bf16)v.z; o[3]=(bf16)v.w;
  *(uint2*)&out[(size_t)i*4] = *(uint2*)o;
}

// ---- fp32 [E][R][C] -> bf16 [E][C][R] transpose+convert ----
__global__ __launch_bounds__(256) void k_tcvt2(const float* __restrict__ in0,
                                               const float* __restrict__ in1,
                                               bf16* __restrict__ out0,
                                               bf16* __restrict__ out1, int R, int C) {
  __shared__ __align__(16) bf16 t[64][72];
  const int z = blockIdx.z;
  const int e = z & (NEXP-1);
  const float* __restrict__ pin = ((z < NEXP) ? in0 : in1) + (size_t)e*R*C;
  bf16* __restrict__ pout = ((z < NEXP) ? out0 : out1) + (size_t)e*R*C;
  const int c0 = blockIdx.x*64, r0 = blockIdx.y*64;
  const int tid = threadIdx.x;
  const int rr = tid>>4, cc4 = (tid&15)*4;
#pragma unroll
  for (int i=0;i<4;i++){
    int r = i*16 + rr;
    float4 v = *(const float4*)&pin[(size_t)(r0+r)*C + c0 + cc4];
    t[cc4+0][r]=(bf16)v.x; t[cc4+1][r]=(bf16)v.y;
    t[cc4+2][r]=(bf16)v.z; t[cc4+3][r]=(bf16)v.w;
  }
  __syncthreads();
#pragma unroll
  for (int i=0;i<4;i++){
    int c = i*16 + rr;
    *(uint2*)&pout[(size_t)(c0+c)*R + r0 + cc4] = *(uint2*)&t[c][cc4];
  }
}

// ---- routing: count tokens per expert ----
__global__ __launch_bounds__(256) void k_count(const float* __restrict__ disp,
                                               int* __restrict__ cnt) {
  __shared__ int lc[NEXP];
  int t = threadIdx.x;
  if (t < NEXP) lc[t] = 0;
  __syncthreads();
  int m = blockIdx.x*256 + t;
  float4 d0 = *(const float4*)&disp[(size_t)m*NEXP];
  float4 d1 = *(const float4*)&disp[(size_t)m*NEXP+4];
  if (d0.x>0.f) atomicAdd(&lc[0],1);
  if (d0.y>0.f) atomicAdd(&lc[1],1);
  if (d0.z>0.f) atomicAdd(&lc[2],1);
  if (d0.w>0.f) atomicAdd(&lc[3],1);
  if (d1.x>0.f) atomicAdd(&lc[4],1);
  if (d1.y>0.f) atomicAdd(&lc[5],1);
  if (d1.z>0.f) atomicAdd(&lc[6],1);
  if (d1.w>0.f) atomicAdd(&lc[7],1);
  __syncthreads();
  if (t < NEXP) atomicAdd(&cnt[t], lc[t]);
}

// ---- prefix + tile list ----
__global__ void k_scan(const int* __restrict__ cnt, int* __restrict__ base,
                       int* __restrict__ te, int* __restrict__ trow, int* __restrict__ tn) {
  __shared__ int sb[NEXP+1], st[NEXP+1], sc[NEXP];
  if (threadIdx.x == 0){
    int b=0, t=0;
    for (int e=0;e<NEXP;e++){
      sb[e]=b; st[e]=t; sc[e]=cnt[e]; base[e]=b;
      b += sc[e];
      t += (sc[e]+TM-1)/TM;
    }
    sb[NEXP]=b; st[NEXP]=t;
  }
  __syncthreads();
  for (int idx=threadIdx.x; idx<MT; idx+=blockDim.x){
    int e=-1;
#pragma unroll
    for (int q=0;q<NEXP;q++) if (idx>=st[q] && idx<st[q+1]) e=q;
    if (e>=0){
      int k = idx - st[e];
      int nr = sc[e] - k*TM; if (nr>TM) nr=TM;
      te[idx]=e; trow[idx]=sb[e]+k*TM; tn[idx]=nr;
    } else te[idx]=-1;
  }
}

// ---- fill slot lists + per-token slot map ----
__global__ __launch_bounds__(256) void k_fill(const float* __restrict__ disp,
    const float* __restrict__ comb, const float* __restrict__ scales,
    const int* __restrict__ base, int* __restrict__ fillc,
    int* __restrict__ stok, float* __restrict__ sw, int* __restrict__ sslot) {
  int m = blockIdx.x*256 + threadIdx.x;
  int jj = 0;
#pragma unroll
  for (int e=0;e<NEXP;e++){
    float dv = disp[(size_t)m*NEXP + e];
    if (dv > 0.f) {
      int s = atomicAdd(&fillc[e], 1);
      int g = base[e] + s;
      stok[g] = m;
      sw[g] = comb[(size_t)m*NEXP + e] * scales[e];
      if (jj < 2) sslot[m*2 + jj] = g;
      jj++;
    }
  }
}

// ---- GEMM1: H1 = gelu(X@Wg)*(X@Wv); 128M x 64N dual-B, 2-phase dbuf ----
__global__ __launch_bounds__(256) void k_gemm1(const bf16* __restrict__ Xb,
    const bf16* __restrict__ WgT, const bf16* __restrict__ WvT,
    const int* __restrict__ te, const int* __restrict__ trow, const int* __restrict__ tn,
    const int* __restrict__ stok, bf16* __restrict__ H1) {
  const int tile = blockIdx.y;
  const int e = te[tile];
  if (e < 0) return;
  const int row0 = trow[tile], nrows = tn[tile];
  const int n0 = blockIdx.x*64;
  __shared__ __align__(16) bf16 Al[2*TM*64];    // 32 KB
  __shared__ __align__(16) bf16 Bgl[2*64*64];   // 16 KB
  __shared__ __align__(16) bf16 Bvl[2*64*64];   // 16 KB
  const int tid = threadIdx.x, lane = tid&63;
  const int wr = (tid>>7)&1, wc = (tid>>6)&1;
  const bf16* __restrict__ wg = WgT + (size_t)e*HID*DIM;  // [H][D], K contiguous
  const bf16* __restrict__ wv = WvT + (size_t)e*HID*DIM;

  // per-lane sources with inverse swizzle: 16B-chunk col q -> q ^ (row&7)
  const bf16* asrc[4];
#pragma unroll
  for (int i=0;i<4;i++){
    int c = i*256 + tid;
    int r = c>>3, qs = (c&7) ^ (r&7);
    int gr = (r < nrows) ? (row0 + r) : row0;
    asrc[i] = Xb + (size_t)stok[gr]*DIM + qs*8;
  }
  const bf16 *bsg[2], *bsv[2];
#pragma unroll
  for (int j=0;j<2;j++){
    int c = j*256 + tid;
    int r = c>>3, qs = (c&7) ^ (r&7);
    size_t o = (size_t)(n0 + r)*DIM + qs*8;
    bsg[j] = wg + o; bsv[j] = wv + o;
  }
  const int wbase = (tid&192)*8;   // wave-uniform LDS chunk base (elems)

  auto stage = [&](int bi, int kt){
    const int k0 = kt*64;
#pragma unroll
    for (int i=0;i<4;i++)
      gload16(asrc[i]+k0, Al + bi*TM*64 + i*2048 + wbase);
#pragma unroll
    for (int j=0;j<2;j++){
      gload16(bsg[j]+k0, Bgl + bi*64*64 + j*2048 + wbase);
      gload16(bsv[j]+k0, Bvl + bi*64*64 + j*2048 + wbase);
    }
  };

  f32x4 accg[4][2] = {}, accv[4][2] = {};
  const int rsw = (lane&7)<<3;     // read-side XOR (row&7 == lane&7 for frag rows)
  stage(0, 0);
  for (int kt=0; kt<DIM/64; ++kt){
    const int bi = kt&1;
    if (kt+1 < DIM/64){ stage(bi^1, kt+1); WAITVM(8); }
    else WAITVM(0);
    BAR(); SCHED0;
#pragma unroll
    for (int ks=0; ks<2; ks++){
      const int kos = (ks*32 + (lane>>4)*8) ^ rsw;
      bf16x8 a[4], bg[2], bv[2];
#pragma unroll
      for (int ni=0; ni<2; ni++){
        bg[ni] = *(const bf16x8*)&Bgl[bi*4096 + (wc*32 + ni*16 + (lane&15))*64 + kos];
        bv[ni] = *(const bf16x8*)&Bvl[bi*4096 + (wc*32 + ni*16 + (lane&15))*64 + kos];
      }
#pragma unroll
      for (int mi=0; mi<4; mi++)
        a[mi] = *(const bf16x8*)&Al[bi*TM*64 + (wr*64 + mi*16 + (lane&15))*64 + kos];
#pragma unroll
      for (int mi=0; mi<4; mi++)
#pragma unroll
        for (int ni=0; ni<2; ni++){
          accg[mi][ni] = __builtin_amdgcn_mfma_f32_16x16x32_bf16(a[mi], bg[ni], accg[mi][ni], 0,0,0);
          accv[mi][ni] = __builtin_amdgcn_mfma_f32_16x16x32_bf16(a[mi], bv[ni], accv[mi][ni], 0,0,0);
        }
    }
    BAR(); SCHED0;
  }
  const int cb = n0 + wc*32 + (lane&15);
  const int rb = wr*64 + (lane>>4)*4;
#pragma unroll
  for (int mi=0; mi<4; mi++)
#pragma unroll
    for (int j=0; j<4; j++){
      int r = rb + mi*16 + j;
      if (r < nrows){
#pragma unroll
        for (int ni=0; ni<2; ni++){
          float g = accg[mi][ni][j], v = accv[mi][ni][j];
          float ge = 0.5f*g*(1.f + erff(g*0.70710678118654752f));
          H1[(size_t)(row0+r)*HID + cb + ni*16] = (bf16)(ge*v);
        }
      }
    }
}

// ---- GEMM2: gout[slot] = (H1@Wo)*sw; 128x128, 2-phase dbuf, plain stores ----
__global__ __launch_bounds__(256) void k_gemm2(const bf16* __restrict__ H1,
    const bf16* __restrict__ WoT,
    const int* __restrict__ te, const int* __restrict__ trow, const int* __restrict__ tn,
    const float* __restrict__ sw, float* __restrict__ gout) {
  const int tile = blockIdx.y;
  const int e = te[tile];
  if (e < 0) return;
  const int row0 = trow[tile], nrows = tn[tile];
  const int n0 = blockIdx.x*128;
  __shared__ __align__(16) bf16 Al[2*TM*64];   // 32 KB
  __shared__ __align__(16) bf16 Bl[2*TM*64];   // 32 KB
  const int tid = threadIdx.x, lane = tid&63;
  const int wr = (tid>>7)&1, wc = (tid>>6)&1;
  const bf16* __restrict__ wo = WoT + (size_t)e*DIM*HID;  // [D][H], K contiguous

  const bf16 *asrc[4], *bsrc[4];
#pragma unroll
  for (int i=0;i<4;i++){
    int c = i*256 + tid;
    int r = c>>3, qs = (c&7) ^ (r&7);
    int ar = (r < nrows) ? (row0 + r) : row0;   // slot index (H1 is per-slot)
    asrc[i] = H1 + (size_t)ar*HID + qs*8;
    bsrc[i] = wo + (size_t)(n0 + r)*HID + qs*8;
  }
  const int wbase = (tid&192)*8;

  auto stage = [&](int bi, int kt){
    const int k0 = kt*64;
#pragma unroll
    for (int i=0;i<4;i++){
      gload16(asrc[i]+k0, Al + bi*TM*64 + i*2048 + wbase);
      gload16(bsrc[i]+k0, Bl + bi*TM*64 + i*2048 + wbase);
    }
  };

  f32x4 acc[4][4] = {};
  const int rsw = (lane&7)<<3;
  stage(0, 0);
  for (int kt=0; kt<HID/64; ++kt){
    const int bi = kt&1;
    if (kt+1 < HID/64){ stage(bi^1, kt+1); WAITVM(8); }
    else WAITVM(0);
    BAR(); SCHED0;
#pragma unroll
    for (int ks=0; ks<2; ks++){
      const int kos = (ks*32 + (lane>>4)*8) ^ rsw;
      bf16x8 a[4], b[4];
#pragma unroll
      for (int ni=0; ni<4; ni++)
        b[ni] = *(const bf16x8*)&Bl[bi*TM*64 + (wc*64 + ni*16 + (lane&15))*64 + kos];
#pragma unroll
      for (int mi=0; mi<4; mi++)
        a[mi] = *(const bf16x8*)&Al[bi*TM*64 + (wr*64 + mi*16 + (lane&15))*64 + kos];
#pragma unroll
      for (int mi=0; mi<4; mi++)
#pragma unroll
        for (int ni=0; ni<4; ni++)
          acc[mi][ni] = __builtin_amdgcn_mfma_f32_16x16x32_bf16(a[mi], b[ni], acc[mi][ni], 0,0,0);
    }
    BAR(); SCHED0;
  }
  const int cb = n0 + wc*64 + (lane&15);
  const int rb = wr*64 + (lane>>4)*4;
#pragma unroll
  for (int mi=0; mi<4; mi++)
#pragma unroll
    for (int j=0; j<4; j++){
      int r = rb + mi*16 + j;
      if (r < nrows){
        int slot = row0 + r;
        float wgt = sw[slot];
        float* op = gout + (size_t)slot*DIM + cb;
#pragma unroll
        for (int ni=0; ni<4; ni++)
          op[ni*16] = acc[mi][ni][j] * wgt;   // plain store, no atomics
      }
    }
}

// ---- combine: out[tok] = gout[slot0] + gout[slot1] ----
__global__ __launch_bounds__(256) void k_comb(const float* __restrict__ gout,
    const int* __restrict__ sslot, float* __restrict__ out) {
  int idx = blockIdx.x*256 + threadIdx.x;
  int m = idx >> 7, c4 = (idx & 127)*4;
  int s0 = sslot[m*2], s1 = sslot[m*2+1];
  float4 x = *(const float4*)&gout[(size_t)s0*DIM + c4];
  float4 y = *(const float4*)&gout[(size_t)s1*DIM + c4];
  x.x += y.x; x.y += y.y; x.z += y.z; x.w += y.w;
  *(float4*)&out[(size_t)m*DIM + c4] = x;
}

extern "C" void kernel_launch(void* const* d_in, const int* in_sizes, int n_in,
                              void* d_out, int out_size, void* d_ws, size_t ws_size,
                              hipStream_t stream) {
  const float* tokens = (const float*)d_in[0];
  const float* disp   = (const float*)d_in[1];
  const float* comb   = (const float*)d_in[2];
  const float* Wg     = (const float*)d_in[3];
  const float* Wv     = (const float*)d_in[4];
  const float* Wo     = (const float*)d_in[5];
  const float* scales = (const float*)d_in[6];
  float* out = (float*)d_out;

  size_t off = 0;
  char* wsb = (char*)d_ws;
  auto take = [&](size_t bytes)->char* {
    char* q = wsb + off; off += (bytes + 255) & ~(size_t)255; return q;
  };
  int*   cnt   = (int*)  take(NEXP*4);
  int*   basee = (int*)  take(NEXP*4);
  int*   fillc = (int*)  take(NEXP*4);
  int*   te    = (int*)  take(MT*4);
  int*   trow  = (int*)  take(MT*4);
  int*   tnr   = (int*)  take(MT*4);
  int*   stok  = (int*)  take((size_t)PMAX*4);
  float* sw    = (float*)take((size_t)PMAX*4);
  int*   sslot = (int*)  take((size_t)MTOK*2*4);
  bf16*  Xb    = (bf16*) take((size_t)MTOK*DIM*2);
  bf16*  WgT   = (bf16*) take((size_t)NEXP*DIM*HID*2);
  bf16*  WvT   = (bf16*) take((size_t)NEXP*DIM*HID*2);
  bf16*  WoT   = (bf16*) take((size_t)NEXP*DIM*HID*2);
  bf16*  H1    = (bf16*) take((size_t)PMAX*HID*2);
  // gout aliases WgT+WvT (2 x 16 MiB contiguous, dead after gemm1; gout = 32 MiB)
  float* gout  = (float*)WgT;
  (void)ws_size; (void)in_sizes; (void)n_in; (void)out_size;

  hipMemsetAsync(d_ws, 0, 768, stream);

  k_cvt_x<<<dim3((MTOK*DIM/4)/256), 256, 0, stream>>>(tokens, Xb, MTOK*DIM/4);
  k_tcvt2<<<dim3(HID/64, DIM/64, 2*NEXP), 256, 0, stream>>>(Wg, Wv, WgT, WvT, DIM, HID);
  k_tcvt2<<<dim3(DIM/64, HID/64, NEXP), 256, 0, stream>>>(Wo, Wo, WoT, WoT, HID, DIM);
  k_count<<<dim3(MTOK/256), 256, 0, stream>>>(disp, cnt);
  k_scan <<<1, 64, 0, stream>>>(cnt, basee, te, trow, tnr);
  k_fill <<<dim3(MTOK/256), 256, 0, stream>>>(disp, comb, scales, basee, fillc, stok, sw, sslot);
  k_gemm1<<<dim3(HID/64, MT), 256, 0, stream>>>(Xb, WgT, WvT, te, trow, tnr, stok, H1);
  k_gemm2<<<dim3(DIM/128, MT), 256, 0, stream>>>(H1, WoT, te, trow, tnr, sw, gout);
  k_comb <<<dim3(MTOK*DIM/4/256), 256, 0, stream>>>(gout, sslot, out);
}

// Round 9
// 229.696 us; speedup vs baseline: 1.2483x; 1.0851x over previous
//
#include <hip/hip_runtime.h>
#include <hip/hip_bf16.h>

// MoE expert pool: E=8, D=512, H=2048, M=8192 tokens, top-2 routing.
// R9: gemm1 BK=32 / 32KB LDS -> ~5 blocks/CU (TLP is the proven mechanism here);
//     gemm2 XCD-bijective swizzle (4 n-blocks of an m-tile share one XCD's L2 for H1);
//     gout plain stores + k_comb (R5-proven), merged transposes.

#define NEXP 8
#define DIM 512
#define HID 2048
#define MTOK 8192
#define PMAX (2*MTOK)
#define TM 128
#define MT 144

typedef __bf16 bf16;
typedef __bf16 bf16x8 __attribute__((ext_vector_type(8)));
typedef float  f32x4  __attribute__((ext_vector_type(4)));

#define WAITVM(N) asm volatile("s_waitcnt vmcnt(" #N ")" ::: "memory")
#define SCHED0    __builtin_amdgcn_sched_barrier(0)
#define BAR       __builtin_amdgcn_s_barrier

__device__ __forceinline__ void gload16(const bf16* g, bf16* l) {
  __builtin_amdgcn_global_load_lds(
      (const __attribute__((address_space(1))) void*)g,
      (__attribute__((address_space(3))) void*)l, 16, 0, 0);
}

// ---- fp32 -> bf16 convert (tokens) ----
__global__ __launch_bounds__(256) void k_cvt_x(const float* __restrict__ in,
                                               bf16* __restrict__ out, int n4) {
  int i = blockIdx.x*256 + threadIdx.x;
  if (i >= n4) return;
  float4 v = ((const float4* __restrict__)in)[i];
  bf16 o[4];
  o[0]=(bf16)v.x; o[1]=(bf16)v.y; o[2]=(bf16)v.z; o[3]=(bf16)v.w;
  *(uint2*)&out[(size_t)i*4] = *(uint2*)o;
}

// ---- fp32 [E][R][C] -> bf16 [E][C][R] transpose+convert ----
__global__ __launch_bounds__(256) void k_tcvt2(const float* __restrict__ in0,
                                               const float* __restrict__ in1,
                                               bf16* __restrict__ out0,
                                               bf16* __restrict__ out1, int R, int C) {
  __shared__ __align__(16) bf16 t[64][72];
  const int z = blockIdx.z;
  const int e = z & (NEXP-1);
  const float* __restrict__ pin = ((z < NEXP) ? in0 : in1) + (size_t)e*R*C;
  bf16* __restrict__ pout = ((z < NEXP) ? out0 : out1) + (size_t)e*R*C;
  const int c0 = blockIdx.x*64, r0 = blockIdx.y*64;
  const int tid = threadIdx.x;
  const int rr = tid>>4, cc4 = (tid&15)*4;
#pragma unroll
  for (int i=0;i<4;i++){
    int r = i*16 + rr;
    float4 v = *(const float4*)&pin[(size_t)(r0+r)*C + c0 + cc4];
    t[cc4+0][r]=(bf16)v.x; t[cc4+1][r]=(bf16)v.y;
    t[cc4+2][r]=(bf16)v.z; t[cc4+3][r]=(bf16)v.w;
  }
  __syncthreads();
#pragma unroll
  for (int i=0;i<4;i++){
    int c = i*16 + rr;
    *(uint2*)&pout[(size_t)(c0+c)*R + r0 + cc4] = *(uint2*)&t[c][cc4];
  }
}

// ---- routing: count tokens per expert ----
__global__ __launch_bounds__(256) void k_count(const float* __restrict__ disp,
                                               int* __restrict__ cnt) {
  __shared__ int lc[NEXP];
  int t = threadIdx.x;
  if (t < NEXP) lc[t] = 0;
  __syncthreads();
  int m = blockIdx.x*256 + t;
  float4 d0 = *(const float4*)&disp[(size_t)m*NEXP];
  float4 d1 = *(const float4*)&disp[(size_t)m*NEXP+4];
  if (d0.x>0.f) atomicAdd(&lc[0],1);
  if (d0.y>0.f) atomicAdd(&lc[1],1);
  if (d0.z>0.f) atomicAdd(&lc[2],1);
  if (d0.w>0.f) atomicAdd(&lc[3],1);
  if (d1.x>0.f) atomicAdd(&lc[4],1);
  if (d1.y>0.f) atomicAdd(&lc[5],1);
  if (d1.z>0.f) atomicAdd(&lc[6],1);
  if (d1.w>0.f) atomicAdd(&lc[7],1);
  __syncthreads();
  if (t < NEXP) atomicAdd(&cnt[t], lc[t]);
}

// ---- prefix + tile list ----
__global__ void k_scan(const int* __restrict__ cnt, int* __restrict__ base,
                       int* __restrict__ te, int* __restrict__ trow, int* __restrict__ tn) {
  __shared__ int sb[NEXP+1], st[NEXP+1], sc[NEXP];
  if (threadIdx.x == 0){
    int b=0, t=0;
    for (int e=0;e<NEXP;e++){
      sb[e]=b; st[e]=t; sc[e]=cnt[e]; base[e]=b;
      b += sc[e];
      t += (sc[e]+TM-1)/TM;
    }
    sb[NEXP]=b; st[NEXP]=t;
  }
  __syncthreads();
  for (int idx=threadIdx.x; idx<MT; idx+=blockDim.x){
    int e=-1;
#pragma unroll
    for (int q=0;q<NEXP;q++) if (idx>=st[q] && idx<st[q+1]) e=q;
    if (e>=0){
      int k = idx - st[e];
      int nr = sc[e] - k*TM; if (nr>TM) nr=TM;
      te[idx]=e; trow[idx]=sb[e]+k*TM; tn[idx]=nr;
    } else te[idx]=-1;
  }
}

// ---- fill slot lists + per-token slot map ----
__global__ __launch_bounds__(256) void k_fill(const float* __restrict__ disp,
    const float* __restrict__ comb, const float* __restrict__ scales,
    const int* __restrict__ base, int* __restrict__ fillc,
    int* __restrict__ stok, float* __restrict__ sw, int* __restrict__ sslot) {
  int m = blockIdx.x*256 + threadIdx.x;
  int jj = 0;
#pragma unroll
  for (int e=0;e<NEXP;e++){
    float dv = disp[(size_t)m*NEXP + e];
    if (dv > 0.f) {
      int s = atomicAdd(&fillc[e], 1);
      int g = base[e] + s;
      stok[g] = m;
      sw[g] = comb[(size_t)m*NEXP + e] * scales[e];
      if (jj < 2) sslot[m*2 + jj] = g;
      jj++;
    }
  }
}

// ---- GEMM1: H1 = gelu(X@Wg)*(X@Wv); 128M x 64N dual-B, BK=32, 32KB LDS ----
// Swizzle: 16B chunk q (of 4) -> q ^ ((row>>1)&3): 2-way banks on ds_read_b128.
__global__ __launch_bounds__(256) void k_gemm1(const bf16* __restrict__ Xb,
    const bf16* __restrict__ WgT, const bf16* __restrict__ WvT,
    const int* __restrict__ te, const int* __restrict__ trow, const int* __restrict__ tn,
    const int* __restrict__ stok, bf16* __restrict__ H1) {
  const int tile = blockIdx.y;
  const int e = te[tile];
  if (e < 0) return;
  const int row0 = trow[tile], nrows = tn[tile];
  const int n0 = blockIdx.x*64;
  __shared__ __align__(16) bf16 Al[2*128*32];   // 16 KB
  __shared__ __align__(16) bf16 Bgl[2*64*32];   // 8 KB
  __shared__ __align__(16) bf16 Bvl[2*64*32];   // 8 KB
  const int tid = threadIdx.x, lane = tid&63;
  const int wr = (tid>>7)&1, wc = (tid>>6)&1;
  const bf16* __restrict__ wg = WgT + (size_t)e*HID*DIM;  // [H][D], K contiguous
  const bf16* __restrict__ wv = WvT + (size_t)e*HID*DIM;

  // staging sources: row r, chunk q of 4; source chunk = q ^ ((r>>1)&3)
  const bf16* asrc[2];
#pragma unroll
  for (int i=0;i<2;i++){
    int c = i*256 + tid;
    int r = c>>2, qs = (c&3) ^ ((r>>1)&3);
    int gr = (r < nrows) ? (row0 + r) : row0;
    asrc[i] = Xb + (size_t)stok[gr]*DIM + qs*8;
  }
  const bf16 *bsg, *bsv;
  {
    int r = tid>>2, qs = (tid&3) ^ ((r>>1)&3);
    size_t o = (size_t)(n0 + r)*DIM + qs*8;
    bsg = wg + o; bsv = wv + o;
  }
  const int wbase = (tid&192)*8;

  auto stage = [&](int bi, int kt){
    const int k0 = kt*32;
    gload16(asrc[0]+k0, Al + bi*4096 + wbase);
    gload16(asrc[1]+k0, Al + bi*4096 + 2048 + wbase);
    gload16(bsg+k0, Bgl + bi*2048 + wbase);
    gload16(bsv+k0, Bvl + bi*2048 + wbase);
  };

  f32x4 accg[4][2] = {}, accv[4][2] = {};
  const int r15 = lane&15;
  const int koff = ((lane>>4) ^ ((r15>>1)&3))*8;
  stage(0, 0);
  for (int kt=0; kt<DIM/32; ++kt){
    const int bi = kt&1;
    if (kt+1 < DIM/32){ stage(bi^1, kt+1); WAITVM(4); }
    else WAITVM(0);
    BAR(); SCHED0;
    bf16x8 a[4], bg[2], bv[2];
#pragma unroll
    for (int ni=0; ni<2; ni++){
      bg[ni] = *(const bf16x8*)&Bgl[bi*2048 + (wc*32 + ni*16 + r15)*32 + koff];
      bv[ni] = *(const bf16x8*)&Bvl[bi*2048 + (wc*32 + ni*16 + r15)*32 + koff];
    }
#pragma unroll
    for (int mi=0; mi<4; mi++)
      a[mi] = *(const bf16x8*)&Al[bi*4096 + (wr*64 + mi*16 + r15)*32 + koff];
#pragma unroll
    for (int mi=0; mi<4; mi++)
#pragma unroll
      for (int ni=0; ni<2; ni++){
        accg[mi][ni] = __builtin_amdgcn_mfma_f32_16x16x32_bf16(a[mi], bg[ni], accg[mi][ni], 0,0,0);
        accv[mi][ni] = __builtin_amdgcn_mfma_f32_16x16x32_bf16(a[mi], bv[ni], accv[mi][ni], 0,0,0);
      }
    BAR(); SCHED0;
  }
  const int cb = n0 + wc*32 + r15;
  const int rb = wr*64 + (lane>>4)*4;
#pragma unroll
  for (int mi=0; mi<4; mi++)
#pragma unroll
    for (int j=0; j<4; j++){
      int r = rb + mi*16 + j;
      if (r < nrows){
#pragma unroll
        for (int ni=0; ni<2; ni++){
          float g = accg[mi][ni][j], v = accv[mi][ni][j];
          float ge = 0.5f*g*(1.f + erff(g*0.70710678118654752f));
          H1[(size_t)(row0+r)*HID + cb + ni*16] = (bf16)(ge*v);
        }
      }
    }
}

// ---- GEMM2: gout[slot] = (H1@Wo)*sw; 128x128, 2-phase dbuf, XCD swizzle ----
// 1D grid 576 = 8 XCDs x 18 m-tiles x 4 n-blocks; all 4 n-blocks of an m-tile
// land on one XCD (xcd = L%8) so the H1 A-tile is fetched once into that L2.
__global__ __launch_bounds__(256) void k_gemm2(const bf16* __restrict__ H1,
    const bf16* __restrict__ WoT,
    const int* __restrict__ te, const int* __restrict__ trow, const int* __restrict__ tn,
    const float* __restrict__ sw, float* __restrict__ gout) {
  const int L = blockIdx.x;
  const int tile = (L&7)*18 + (L>>5);     // bijective: 144 = 8*18
  const int n0 = ((L>>3)&3)*128;
  const int e = te[tile];
  if (e < 0) return;
  const int row0 = trow[tile], nrows = tn[tile];
  __shared__ __align__(16) bf16 Al[2*TM*64];   // 32 KB
  __shared__ __align__(16) bf16 Bl[2*TM*64];   // 32 KB
  const int tid = threadIdx.x, lane = tid&63;
  const int wr = (tid>>7)&1, wc = (tid>>6)&1;
  const bf16* __restrict__ wo = WoT + (size_t)e*DIM*HID;  // [D][H], K contiguous

  const bf16 *asrc[4], *bsrc[4];
#pragma unroll
  for (int i=0;i<4;i++){
    int c = i*256 + tid;
    int r = c>>3, qs = (c&7) ^ (r&7);
    int ar = (r < nrows) ? (row0 + r) : row0;   // slot index (H1 is per-slot)
    asrc[i] = H1 + (size_t)ar*HID + qs*8;
    bsrc[i] = wo + (size_t)(n0 + r)*HID + qs*8;
  }
  const int wbase = (tid&192)*8;

  auto stage = [&](int bi, int kt){
    const int k0 = kt*64;
#pragma unroll
    for (int i=0;i<4;i++){
      gload16(asrc[i]+k0, Al + bi*TM*64 + i*2048 + wbase);
      gload16(bsrc[i]+k0, Bl + bi*TM*64 + i*2048 + wbase);
    }
  };

  f32x4 acc[4][4] = {};
  const int rsw = (lane&7)<<3;
  stage(0, 0);
  for (int kt=0; kt<HID/64; ++kt){
    const int bi = kt&1;
    if (kt+1 < HID/64){ stage(bi^1, kt+1); WAITVM(8); }
    else WAITVM(0);
    BAR(); SCHED0;
#pragma unroll
    for (int ks=0; ks<2; ks++){
      const int kos = (ks*32 + (lane>>4)*8) ^ rsw;
      bf16x8 a[4], b[4];
#pragma unroll
      for (int ni=0; ni<4; ni++)
        b[ni] = *(const bf16x8*)&Bl[bi*TM*64 + (wc*64 + ni*16 + (lane&15))*64 + kos];
#pragma unroll
      for (int mi=0; mi<4; mi++)
        a[mi] = *(const bf16x8*)&Al[bi*TM*64 + (wr*64 + mi*16 + (lane&15))*64 + kos];
#pragma unroll
      for (int mi=0; mi<4; mi++)
#pragma unroll
        for (int ni=0; ni<4; ni++)
          acc[mi][ni] = __builtin_amdgcn_mfma_f32_16x16x32_bf16(a[mi], b[ni], acc[mi][ni], 0,0,0);
    }
    BAR(); SCHED0;
  }
  const int cb = n0 + wc*64 + (lane&15);
  const int rb = wr*64 + (lane>>4)*4;
#pragma unroll
  for (int mi=0; mi<4; mi++)
#pragma unroll
    for (int j=0; j<4; j++){
      int r = rb + mi*16 + j;
      if (r < nrows){
        int slot = row0 + r;
        float wgt = sw[slot];
        float* op = gout + (size_t)slot*DIM + cb;
#pragma unroll
        for (int ni=0; ni<4; ni++)
          op[ni*16] = acc[mi][ni][j] * wgt;   // plain store, no atomics
      }
    }
}

// ---- combine: out[tok] = gout[slot0] + gout[slot1] ----
__global__ __launch_bounds__(256) void k_comb(const float* __restrict__ gout,
    const int* __restrict__ sslot, float* __restrict__ out) {
  int idx = blockIdx.x*256 + threadIdx.x;
  int m = idx >> 7, c4 = (idx & 127)*4;
  int s0 = sslot[m*2], s1 = sslot[m*2+1];
  float4 x = *(const float4*)&gout[(size_t)s0*DIM + c4];
  float4 y = *(const float4*)&gout[(size_t)s1*DIM + c4];
  x.x += y.x; x.y += y.y; x.z += y.z; x.w += y.w;
  *(float4*)&out[(size_t)m*DIM + c4] = x;
}

extern "C" void kernel_launch(void* const* d_in, const int* in_sizes, int n_in,
                              void* d_out, int out_size, void* d_ws, size_t ws_size,
                              hipStream_t stream) {
  const float* tokens = (const float*)d_in[0];
  const float* disp   = (const float*)d_in[1];
  const float* comb   = (const float*)d_in[2];
  const float* Wg     = (const float*)d_in[3];
  const float* Wv     = (const float*)d_in[4];
  const float* Wo     = (const float*)d_in[5];
  const float* scales = (const float*)d_in[6];
  float* out = (float*)d_out;

  size_t off = 0;
  char* wsb = (char*)d_ws;
  auto take = [&](size_t bytes)->char* {
    char* q = wsb + off; off += (bytes + 255) & ~(size_t)255; return q;
  };
  int*   cnt   = (int*)  take(NEXP*4);
  int*   basee = (int*)  take(NEXP*4);
  int*   fillc = (int*)  take(NEXP*4);
  int*   te    = (int*)  take(MT*4);
  int*   trow  = (int*)  take(MT*4);
  int*   tnr   = (int*)  take(MT*4);
  int*   stok  = (int*)  take((size_t)PMAX*4);
  float* sw    = (float*)take((size_t)PMAX*4);
  int*   sslot = (int*)  take((size_t)MTOK*2*4);
  bf16*  Xb    = (bf16*) take((size_t)MTOK*DIM*2);
  bf16*  WgT   = (bf16*) take((size_t)NEXP*DIM*HID*2);
  bf16*  WvT   = (bf16*) take((size_t)NEXP*DIM*HID*2);
  bf16*  WoT   = (bf16*) take((size_t)NEXP*DIM*HID*2);
  bf16*  H1    = (bf16*) take((size_t)PMAX*HID*2);
  // gout aliases WgT+WvT (2 x 16 MiB contiguous, dead after gemm1; gout = 32 MiB)
  float* gout  = (float*)WgT;
  (void)ws_size; (void)in_sizes; (void)n_in; (void)out_size;

  hipMemsetAsync(d_ws, 0, 768, stream);

  k_cvt_x<<<dim3((MTOK*DIM/4)/256), 256, 0, stream>>>(tokens, Xb, MTOK*DIM/4);
  k_tcvt2<<<dim3(HID/64, DIM/64, 2*NEXP), 256, 0, stream>>>(Wg, Wv, WgT, WvT, DIM, HID);
  k_tcvt2<<<dim3(DIM/64, HID/64, NEXP), 256, 0, stream>>>(Wo, Wo, WoT, WoT, HID, DIM);
  k_count<<<dim3(MTOK/256), 256, 0, stream>>>(disp, cnt);
  k_scan <<<1, 64, 0, stream>>>(cnt, basee, te, trow, tnr);
  k_fill <<<dim3(MTOK/256), 256, 0, stream>>>(disp, comb, scales, basee, fillc, stok, sw, sslot);
  k_gemm1<<<dim3(HID/64, MT), 256, 0, stream>>>(Xb, WgT, WvT, te, trow, tnr, stok, H1);
  k_gemm2<<<dim3(8*18*4), 256, 0, stream>>>(H1, WoT, te, trow, tnr, sw, gout);
  k_comb <<<dim3(MTOK*DIM/4/256), 256, 0, stream>>>(gout, sslot, out);
}